// Round 8
// baseline (3001.674 us; speedup 1.0000x reference)
//
#include <hip/hip_runtime.h>
#include <cstdint>

#define T_DIM 512
#define B_DIM 64
#define I_DIM 256
#define H_DIM 512

typedef short bf16x8 __attribute__((ext_vector_type(8)));
typedef float f32x4  __attribute__((ext_vector_type(4)));
typedef unsigned int u32x4 __attribute__((ext_vector_type(4)));
typedef unsigned int u32x2 __attribute__((ext_vector_type(2)));

union BF8U { bf16x8 v; u32x4 u; };

// ---- ws layout (NO flags, NO init kernel — tags are self-describing) ----
#define WS_STATE   0u
#define GRP_BYTES  131072u                    // 2 slots x 16 batch x 512 k x 8B
#define WS_XPK     (8u*GRP_BYTES)             // 1,048,576
#define XPK_UINTS  (512u*4u*8u*64u*8u)        // 32MB
#define WS_NEED_MIN WS_XPK
#define WS_NEED_XPK (WS_XPK + XPK_UINTS*4u)

__device__ __forceinline__ short f2bf(float f) {
  unsigned u = __float_as_uint(f);
  unsigned r = (u + 0x7FFFu + ((u >> 16) & 1u)) >> 16;  // RNE
  return (short)r;
}
__device__ __forceinline__ float bf2f(short s) {
  return __uint_as_float(((unsigned)(unsigned short)s) << 16);
}
__device__ __forceinline__ float sigm(float v) { return 1.0f / (1.0f + __expf(-v)); }
__device__ __forceinline__ float tanh_f(float v) {
  float e = __expf(2.0f * fabsf(v));
  float r = 1.0f - 2.0f / (e + 1.0f);
  return copysignf(r, v);
}

// agent-scope coherence-point store (PROVEN R2/R3/R7): sc0 sc1
__device__ __forceinline__ void st_u32x2(unsigned* p, u32x2 v) {
  asm volatile("global_store_dwordx2 %0, %1, off sc0 sc1" :: "v"(p), "v"(v) : "memory");
}

// pre-pack x into per-lane MFMA fragments: [t][mt][kt(8)][lane(64)][hi x4, lo x4] uints
__global__ void __launch_bounds__(256) xpack_kernel(const float* __restrict__ x,
                                                    unsigned* __restrict__ xpk) {
  size_t idx = (size_t)blockIdx.x * 256 + threadIdx.x;   // 1,048,576 total
  int l = (int)(idx & 63);
  size_t kt = (idx >> 6) & 7, mt = (idx >> 9) & 3, t = idx >> 11;
  const float* xp = x + ((t * 64) + mt * 16 + (size_t)(l & 15)) * 256 + kt * 32 + (size_t)(l >> 4) * 8;
  f32x4 a = *(const f32x4*)xp, b = *(const f32x4*)(xp + 4);
  float v[8] = {a[0], a[1], a[2], a[3], b[0], b[1], b[2], b[3]};
  u32x4 hi, lo;
  #pragma unroll
  for (int i = 0; i < 4; ++i) {
    short h0 = f2bf(v[2 * i]), h1 = f2bf(v[2 * i + 1]);
    short l0 = f2bf(v[2 * i] - bf2f(h0)), l1 = f2bf(v[2 * i + 1] - bf2f(h1));
    hi[i] = (unsigned)(unsigned short)h0 | ((unsigned)(unsigned short)h1 << 16);
    lo[i] = (unsigned)(unsigned short)l0 | ((unsigned)(unsigned short)l1 << 16);
  }
  unsigned* dst = xpk + idx * 8;
  *(u32x4*)dst = hi;
  *(u32x4*)(dst + 4) = lo;
}

// 256 blocks x 256 threads (PROVEN geometry). Group g = blockIdx&7, 32 blocks/group,
// block owns 16 cols (js). Wave w: x k=[64w,64w+64), h/c k=[128w,128w+128).
// Sync: 4-bit step tag (t&15) embedded in lo-word lsbs of each 8B state granule.
// Consumers load speculatively and verify tags; no flags, no drains, no release.
template <bool XPK>
__global__ void __launch_bounds__(256, 1) lstm_kernel(
    const float* __restrict__ x, const float* __restrict__ tim,
    const float* __restrict__ Wih_f, const float* __restrict__ Whh_f,
    const float* __restrict__ bias_f, const float* __restrict__ Wd_f,
    const float* __restrict__ bd_f,
    const float* __restrict__ Wih_b, const float* __restrict__ Whh_b,
    const float* __restrict__ bias_b, const float* __restrict__ Wd_b,
    const float* __restrict__ bd_b,
    float* __restrict__ out, char* __restrict__ wsb,
    const unsigned* __restrict__ xpk)
{
  const int tid = threadIdx.x;
  const int w   = tid >> 6;
  const int l   = tid & 63;
  const int lw  = l & 15;
  const int ko  = l >> 4;
  const int g   = blockIdx.x & 7;
  const int js  = blockIdx.x >> 3;        // 0..31
  const int dir = g & 1;
  const int mt  = g >> 1;
  const int b0  = mt * 16;

  const float* Wih  = dir ? Wih_b  : Wih_f;
  const float* Whh  = dir ? Whh_b  : Whh_f;
  const float* bias = dir ? bias_b : bias_f;
  const float* Wd   = dir ? Wd_b   : Wd_f;
  const float* bd   = dir ? bd_b   : bd_f;

  unsigned* state = (unsigned*)(wsb + WS_STATE) + (size_t)g * (GRP_BYTES / 4);
  // state: uint2[slot(2)][batch(16)][k(512)] = (h_hi<<16|h_lo', c_hi<<16|c_lo')
  // where lo' lsb[1:0] carry tag bits.

  __shared__ float red[2][4][5][16][18];  // double-buffered -> ONE barrier/step; 46KB

  // ---- weight preload (hi/lo bf16 split), persists all 512 steps ----
  bf16x8 wxh[4][2], wxl[4][2];
  bf16x8 whh[4][4], whl[4][4];
  bf16x8 wdh[4],    wdl[4];
  #pragma unroll
  for (int xi = 0; xi < 2; ++xi) {
    const int krow = (w * 2 + xi) * 32 + ko * 8;
    #pragma unroll
    for (int g4 = 0; g4 < 4; ++g4) {
      const float* p = Wih + (size_t)krow * 2048 + g4 * 512 + js * 16 + lw;
      #pragma unroll
      for (int i = 0; i < 8; ++i) {
        float v = p[(size_t)i * 2048];
        short hi = f2bf(v);
        wxh[g4][xi][i] = hi;
        wxl[g4][xi][i] = f2bf(v - bf2f(hi));
      }
    }
  }
  #pragma unroll
  for (int q = 0; q < 4; ++q) {
    const int krow = w * 128 + q * 32 + ko * 8;
    #pragma unroll
    for (int g4 = 0; g4 < 4; ++g4) {
      const float* p = Whh + (size_t)krow * 2048 + g4 * 512 + js * 16 + lw;
      #pragma unroll
      for (int i = 0; i < 8; ++i) {
        float v = p[(size_t)i * 2048];
        short hi = f2bf(v);
        whh[g4][q][i] = hi;
        whl[g4][q][i] = f2bf(v - bf2f(hi));
      }
    }
    const float* p2 = Wd + (size_t)krow * 512 + js * 16 + lw;
    #pragma unroll
    for (int i = 0; i < 8; ++i) {
      float v = p2[(size_t)i * 512];
      short hi = f2bf(v);
      wdh[q][i] = hi;
      wdl[q][i] = f2bf(v - bf2f(hi));
    }
  }

  const int ub = tid >> 4;
  const int uj = tid & 15;
  const int jglob = js * 16 + uj;
  const float bs_i = bias[jglob];
  const float bs_f = bias[512 + jglob];
  const float bs_g = bias[1024 + jglob];
  const float bs_o = bias[1536 + jglob];
  const float bs_d = bd[jglob];
  float c_reg = 0.0f;

  u32x4 rr[4][4];
  auto issue_q = [&](int qq, int lslot) {
    const unsigned* sp = state + 2u * ((size_t)lslot * 8192 + (size_t)lw * 512 + w * 128 + qq * 32 + ko * 8);
    asm volatile(
        "global_load_dwordx4 %0, %4, off sc0 sc1\n\t"
        "global_load_dwordx4 %1, %4, off offset:16 sc0 sc1\n\t"
        "global_load_dwordx4 %2, %4, off offset:32 sc0 sc1\n\t"
        "global_load_dwordx4 %3, %4, off offset:48 sc0 sc1"
        : "=&v"(rr[qq][0]), "=&v"(rr[qq][1]), "=&v"(rr[qq][2]), "=&v"(rr[qq][3])
        : "v"(sp) : "memory");
  };

  for (int t = 0; t < T_DIM; ++t) {
    const int tsrc = dir ? (T_DIM - 1 - t) : t;
    const int sslot = t & 1;              // producer writes slot t&1, tag t&15
    const int lslot = sslot ^ 1;          // consumer reads slot (t-1)&1, tag (t-1)&15
    const int p = t & 1;                  // red buffer parity

    // ---- S1: issue ALL state loads FIRST (speculative; overlap everything) ----
    if (t > 0) {
      #pragma unroll
      for (int q = 0; q < 4; ++q) issue_q(q, lslot);
    }

    // ---- X phase (x frags + x MFMAs; flight of state loads overlaps) ----
    f32x4 ag[4][2]; f32x4 ac[2];
    #pragma unroll
    for (int g4 = 0; g4 < 4; ++g4) { ag[g4][0] = (f32x4)0.0f; ag[g4][1] = (f32x4)0.0f; }
    ac[0] = (f32x4)0.0f; ac[1] = (f32x4)0.0f;

    float tt = tim[(size_t)tsrc * B_DIM + b0 + ub];

    bf16x8 axh[2], axl[2];
    if (XPK) {
      const unsigned* xb = xpk + ((((size_t)tsrc * 4 + mt) * 8 + w * 2) * 64 + l) * 8;
      BF8U h0, l0, h1, l1;
      h0.u = *(const u32x4*)xb;         l0.u = *(const u32x4*)(xb + 4);
      h1.u = *(const u32x4*)(xb + 512); l1.u = *(const u32x4*)(xb + 516);
      axh[0] = h0.v; axl[0] = l0.v; axh[1] = h1.v; axl[1] = l1.v;
    } else {
      #pragma unroll
      for (int xi = 0; xi < 2; ++xi) {
        const float* xp = x + ((size_t)tsrc * B_DIM + b0 + lw) * I_DIM + (w * 2 + xi) * 32 + ko * 8;
        f32x4 v0 = *(const f32x4*)xp;
        f32x4 v1 = *(const f32x4*)(xp + 4);
        bf16x8 vh, vl;
        #pragma unroll
        for (int i = 0; i < 4; ++i) {
          short h0 = f2bf(v0[i]); vh[i] = h0;     vl[i] = f2bf(v0[i] - bf2f(h0));
          short h1 = f2bf(v1[i]); vh[4 + i] = h1; vl[4 + i] = f2bf(v1[i] - bf2f(h1));
        }
        axh[xi] = vh; axl[xi] = vl;
      }
    }
    #pragma unroll
    for (int xi = 0; xi < 2; ++xi) {
      #pragma unroll
      for (int g4 = 0; g4 < 4; ++g4) {
        f32x4 acc = ag[g4][xi];
        acc = __builtin_amdgcn_mfma_f32_16x16x32_bf16(axh[xi], wxh[g4][xi], acc, 0, 0, 0);
        acc = __builtin_amdgcn_mfma_f32_16x16x32_bf16(axl[xi], wxh[g4][xi], acc, 0, 0, 0);
        acc = __builtin_amdgcn_mfma_f32_16x16x32_bf16(axh[xi], wxl[g4][xi], acc, 0, 0, 0);
        ag[g4][xi] = acc;
      }
    }

    // ---- S2: drain once, then per-q tag-verify (retry only if stale) + MFMAs ----
    if (t > 0) {
      asm volatile("s_waitcnt vmcnt(0)" ::: "memory");
      __builtin_amdgcn_sched_barrier(0);
      const unsigned e  = (unsigned)(t - 1) & 15u;
      const unsigned eb = (e & 3u) | (((e >> 2) & 3u) << 2);
      const unsigned P8 = eb | (eb << 4);

      #pragma unroll
      for (int q = 0; q < 4; ++q) {
        while (true) {
          int ok = 1;
          #pragma unroll
          for (int j = 0; j < 4; ++j) {
            unsigned m = (rr[q][j][0] & 3u) | ((rr[q][j][1] & 3u) << 2)
                       | ((rr[q][j][2] & 3u) << 4) | ((rr[q][j][3] & 3u) << 6);
            ok &= (m == P8) ? 1 : 0;
          }
          if (__all(ok)) break;
          issue_q(q, lslot);
          asm volatile("s_waitcnt vmcnt(0)" ::: "memory");
          __builtin_amdgcn_sched_barrier(0);
        }

        BF8U hh_, hl_, ch_, cl_;
        #pragma unroll
        for (int j = 0; j < 4; ++j) {
          unsigned hw0 = rr[q][j][0], cw0 = rr[q][j][1];
          unsigned hw1 = rr[q][j][2], cw1 = rr[q][j][3];
          hh_.u[j] = __builtin_amdgcn_perm(hw1, hw0, 0x07060302u);
          hl_.u[j] = __builtin_amdgcn_perm(hw1, hw0, 0x05040100u);
          ch_.u[j] = __builtin_amdgcn_perm(cw1, cw0, 0x07060302u);
          cl_.u[j] = __builtin_amdgcn_perm(cw1, cw0, 0x05040100u);
        }
        #pragma unroll
        for (int g4 = 0; g4 < 4; ++g4) {
          f32x4 acc = ag[g4][q & 1];
          acc = __builtin_amdgcn_mfma_f32_16x16x32_bf16(hh_.v, whh[g4][q], acc, 0, 0, 0);
          acc = __builtin_amdgcn_mfma_f32_16x16x32_bf16(hl_.v, whh[g4][q], acc, 0, 0, 0);
          acc = __builtin_amdgcn_mfma_f32_16x16x32_bf16(hh_.v, whl[g4][q], acc, 0, 0, 0);
          ag[g4][q & 1] = acc;
        }
        f32x4 a2 = ac[q & 1];
        a2 = __builtin_amdgcn_mfma_f32_16x16x32_bf16(ch_.v, wdh[q], a2, 0, 0, 0);
        a2 = __builtin_amdgcn_mfma_f32_16x16x32_bf16(cl_.v, wdh[q], a2, 0, 0, 0);
        a2 = __builtin_amdgcn_mfma_f32_16x16x32_bf16(ch_.v, wdl[q], a2, 0, 0, 0);
        ac[q & 1] = a2;
      }
    }

    // ---- S2b: cross-wave reduce into red[p] (double-buffered; ONE barrier) ----
    #pragma unroll
    for (int g4 = 0; g4 < 4; ++g4) {
      f32x4 s = ag[g4][0] + ag[g4][1];
      #pragma unroll
      for (int r = 0; r < 4; ++r) red[p][w][g4][ko * 4 + r][lw] = s[r];
    }
    {
      f32x4 s = ac[0] + ac[1];
      #pragma unroll
      for (int r = 0; r < 4; ++r) red[p][w][4][ko * 4 + r][lw] = s[r];
    }
    __syncthreads();

    // ---- S3: update + tagged state store + out store (no drain, no release) ----
    {
      float gi = red[p][0][0][ub][uj] + red[p][1][0][ub][uj] + red[p][2][0][ub][uj] + red[p][3][0][ub][uj] + bs_i;
      float gf = red[p][0][1][ub][uj] + red[p][1][1][ub][uj] + red[p][2][1][ub][uj] + red[p][3][1][ub][uj] + bs_f;
      float gg = red[p][0][2][ub][uj] + red[p][1][2][ub][uj] + red[p][2][2][ub][uj] + red[p][3][2][ub][uj] + bs_g;
      float go = red[p][0][3][ub][uj] + red[p][1][3][ub][uj] + red[p][2][3][ub][uj] + red[p][3][3][ub][uj] + bs_o;
      float csv = red[p][0][4][ub][uj] + red[p][1][4][ub][uj] + red[p][2][4][ub][uj] + red[p][3][4][ub][uj] + bs_d;

      float c_s = tanh_f(csv);
      float dinv = 1.0f / __logf(2.718281828459045f + tt);
      float c_adj = c_reg - c_s + c_s * dinv;
      float iv = sigm(gi);
      float fv = sigm(gf);
      float ov = sigm(go);
      float gv = tanh_f(gg);
      float c_new = fv * c_adj + iv * gv;
      float h_new = ov * tanh_f(c_new);
      c_reg = c_new;

      short hh = f2bf(h_new), hl2 = f2bf(h_new - bf2f(hh));
      short ch = f2bf(c_new), cl2 = f2bf(c_new - bf2f(ch));
      const unsigned tg = (unsigned)t;
      u32x2 val;
      val[0] = ((unsigned)(unsigned short)hh << 16) | (((unsigned)(unsigned short)hl2) & 0xFFFCu) | (tg & 3u);
      val[1] = ((unsigned)(unsigned short)ch << 16) | (((unsigned)(unsigned short)cl2) & 0xFFFCu) | ((tg >> 2) & 3u);
      unsigned* sp = state + 2u * ((size_t)sslot * 8192 + (size_t)ub * 512 + jglob);
      st_u32x2(sp, val);
      out[((size_t)tsrc * B_DIM + b0 + ub) * 1024 + dir * 512 + jglob] = h_new;
    }
    // loop: next step's vmcnt(0) drains these stores while loads fly
  }
}

extern "C" void kernel_launch(void* const* d_in, const int* in_sizes, int n_in,
                              void* d_out, int out_size, void* d_ws, size_t ws_size,
                              hipStream_t stream) {
  (void)in_sizes; (void)n_in; (void)out_size;
  if (ws_size < (size_t)WS_NEED_MIN) return;  // failure signature: ws too small
  const bool use_xpk = ws_size >= (size_t)WS_NEED_XPK;

  const float* x     = (const float*)d_in[0];
  const float* tim   = (const float*)d_in[1];
  const float* Wih_f = (const float*)d_in[2];
  const float* Whh_f = (const float*)d_in[3];
  const float* b_f   = (const float*)d_in[4];
  const float* Wd_f  = (const float*)d_in[5];
  const float* bd_f  = (const float*)d_in[6];
  const float* Wih_b = (const float*)d_in[7];
  const float* Whh_b = (const float*)d_in[8];
  const float* b_b   = (const float*)d_in[9];
  const float* Wd_b  = (const float*)d_in[10];
  const float* bd_b  = (const float*)d_in[11];
  float* out = (float*)d_out;
  char* ws = (char*)d_ws;
  unsigned* xpk = (unsigned*)(ws + WS_XPK);

  if (use_xpk) {
    hipLaunchKernelGGL(xpack_kernel, dim3(4096), dim3(256), 0, stream, x, xpk);
    hipLaunchKernelGGL((lstm_kernel<true>), dim3(256), dim3(256), 0, stream,
                       x, tim, Wih_f, Whh_f, b_f, Wd_f, bd_f,
                       Wih_b, Whh_b, b_b, Wd_b, bd_b, out, ws, xpk);
  } else {
    hipLaunchKernelGGL((lstm_kernel<false>), dim3(256), dim3(256), 0, stream,
                       x, tim, Wih_f, Whh_f, b_f, Wd_f, bd_f,
                       Wih_b, Whh_b, b_b, Wd_b, bd_b, out, ws, (const unsigned*)nullptr);
  }
}

// Round 9
// 2525.074 us; speedup vs baseline: 1.1887x; 1.1887x over previous
//
#include <hip/hip_runtime.h>
#include <cstdint>

#define T_DIM 512
#define B_DIM 64
#define I_DIM 256
#define H_DIM 512

typedef short bf16x8 __attribute__((ext_vector_type(8)));
typedef float f32x4  __attribute__((ext_vector_type(4)));
typedef unsigned int u32x4 __attribute__((ext_vector_type(4)));
typedef unsigned int u32x2 __attribute__((ext_vector_type(2)));

union BF8U { bf16x8 v; u32x4 u; };

// ---- ws layout ----
#define WS_STATE   0u
#define GRP_BYTES  131072u                    // 2 slots x 16 batch x 512 k x 8B
#define WS_XPK     (8u*GRP_BYTES)             // 1,048,576
#define XPK_UINTS  (512u*4u*8u*64u*8u)        // 32MB
#define WS_NEED_MIN WS_XPK
#define WS_NEED_XPK (WS_XPK + XPK_UINTS*4u)

__device__ __forceinline__ short f2bf(float f) {
  unsigned u = __float_as_uint(f);
  unsigned r = (u + 0x7FFFu + ((u >> 16) & 1u)) >> 16;  // RNE
  return (short)r;
}
__device__ __forceinline__ float bf2f(short s) {
  return __uint_as_float(((unsigned)(unsigned short)s) << 16);
}
__device__ __forceinline__ float sigm(float v) { return 1.0f / (1.0f + __expf(-v)); }
__device__ __forceinline__ float tanh_f(float v) {
  float e = __expf(2.0f * fabsf(v));
  float r = 1.0f - 2.0f / (e + 1.0f);
  return copysignf(r, v);
}

// agent-scope coherence-point store (PROVEN R2/R3/R7/R8): sc0 sc1
__device__ __forceinline__ void st_u32x2(unsigned* p, u32x2 v) {
  asm volatile("global_store_dwordx2 %0, %1, off sc0 sc1" :: "v"(p), "v"(v) : "memory");
}

// Replay safety: rewrite state region with tag-5 pattern (word=1 -> granule tag 1|(1<<2)=5,
// which is never the expected tag before the slot has been overwritten by live data).
// Device-scope stores so bypassing (sc0 sc1) readers cannot see pre-init memory.
__global__ void __launch_bounds__(256) init_ws_kernel(unsigned* ws) {
  unsigned n = (8u * GRP_BYTES) / 4u;
  for (unsigned i = blockIdx.x * 256u + threadIdx.x; i < n; i += gridDim.x * 256u)
    __hip_atomic_store(&ws[i], 1u, __ATOMIC_RELAXED, __HIP_MEMORY_SCOPE_AGENT);
}

// pre-pack x into per-lane MFMA fragments: [t][mt][kt(8)][lane(64)][hi x4, lo x4] uints
__global__ void __launch_bounds__(256) xpack_kernel(const float* __restrict__ x,
                                                    unsigned* __restrict__ xpk) {
  size_t idx = (size_t)blockIdx.x * 256 + threadIdx.x;   // 1,048,576 total
  int l = (int)(idx & 63);
  size_t kt = (idx >> 6) & 7, mt = (idx >> 9) & 3, t = idx >> 11;
  const float* xp = x + ((t * 64) + mt * 16 + (size_t)(l & 15)) * 256 + kt * 32 + (size_t)(l >> 4) * 8;
  f32x4 a = *(const f32x4*)xp, b = *(const f32x4*)(xp + 4);
  float v[8] = {a[0], a[1], a[2], a[3], b[0], b[1], b[2], b[3]};
  u32x4 hi, lo;
  #pragma unroll
  for (int i = 0; i < 4; ++i) {
    short h0 = f2bf(v[2 * i]), h1 = f2bf(v[2 * i + 1]);
    short l0 = f2bf(v[2 * i] - bf2f(h0)), l1 = f2bf(v[2 * i + 1] - bf2f(h1));
    hi[i] = (unsigned)(unsigned short)h0 | ((unsigned)(unsigned short)h1 << 16);
    lo[i] = (unsigned)(unsigned short)l0 | ((unsigned)(unsigned short)l1 << 16);
  }
  unsigned* dst = xpk + idx * 8;
  *(u32x4*)dst = hi;
  *(u32x4*)(dst + 4) = lo;
}

// 256 blocks x 256 threads (PROVEN geometry). Group g = blockIdx&7, 32 blocks/group,
// block owns 16 cols (js). Wave w: x k=[64w,64w+64), h/c k=[128w,128w+128).
// Sync: 4-bit step tag embedded in state granules; batched wave-uniform retries;
// xpk register-prefetch pipeline; no flags, no drains, no producer release.
template <bool XPK>
__global__ void __launch_bounds__(256, 1) lstm_kernel(
    const float* __restrict__ x, const float* __restrict__ tim,
    const float* __restrict__ Wih_f, const float* __restrict__ Whh_f,
    const float* __restrict__ bias_f, const float* __restrict__ Wd_f,
    const float* __restrict__ bd_f,
    const float* __restrict__ Wih_b, const float* __restrict__ Whh_b,
    const float* __restrict__ bias_b, const float* __restrict__ Wd_b,
    const float* __restrict__ bd_b,
    float* __restrict__ out, char* __restrict__ wsb,
    const unsigned* __restrict__ xpk)
{
  const int tid = threadIdx.x;
  const int w   = tid >> 6;
  const int l   = tid & 63;
  const int lw  = l & 15;
  const int ko  = l >> 4;
  const int g   = blockIdx.x & 7;
  const int js  = blockIdx.x >> 3;        // 0..31
  const int dir = g & 1;
  const int mt  = g >> 1;
  const int b0  = mt * 16;

  const float* Wih  = dir ? Wih_b  : Wih_f;
  const float* Whh  = dir ? Whh_b  : Whh_f;
  const float* bias = dir ? bias_b : bias_f;
  const float* Wd   = dir ? Wd_b   : Wd_f;
  const float* bd   = dir ? bd_b   : bd_f;

  unsigned* state = (unsigned*)(wsb + WS_STATE) + (size_t)g * (GRP_BYTES / 4);
  // state: uint2[slot(2)][batch(16)][k(512)]; lo-word lsb[1:0] carry tag bits.

  __shared__ float red[2][4][5][16][18];  // double-buffered; ONE barrier/step; 46KB

  // ---- weight preload (hi/lo bf16 split), persists all 512 steps ----
  bf16x8 wxh[4][2], wxl[4][2];
  bf16x8 whh[4][4], whl[4][4];
  bf16x8 wdh[4],    wdl[4];
  #pragma unroll
  for (int xi = 0; xi < 2; ++xi) {
    const int krow = (w * 2 + xi) * 32 + ko * 8;
    #pragma unroll
    for (int g4 = 0; g4 < 4; ++g4) {
      const float* p = Wih + (size_t)krow * 2048 + g4 * 512 + js * 16 + lw;
      #pragma unroll
      for (int i = 0; i < 8; ++i) {
        float v = p[(size_t)i * 2048];
        short hi = f2bf(v);
        wxh[g4][xi][i] = hi;
        wxl[g4][xi][i] = f2bf(v - bf2f(hi));
      }
    }
  }
  #pragma unroll
  for (int q = 0; q < 4; ++q) {
    const int krow = w * 128 + q * 32 + ko * 8;
    #pragma unroll
    for (int g4 = 0; g4 < 4; ++g4) {
      const float* p = Whh + (size_t)krow * 2048 + g4 * 512 + js * 16 + lw;
      #pragma unroll
      for (int i = 0; i < 8; ++i) {
        float v = p[(size_t)i * 2048];
        short hi = f2bf(v);
        whh[g4][q][i] = hi;
        whl[g4][q][i] = f2bf(v - bf2f(hi));
      }
    }
    const float* p2 = Wd + (size_t)krow * 512 + js * 16 + lw;
    #pragma unroll
    for (int i = 0; i < 8; ++i) {
      float v = p2[(size_t)i * 512];
      short hi = f2bf(v);
      wdh[q][i] = hi;
      wdl[q][i] = f2bf(v - bf2f(hi));
    }
  }

  const int ub = tid >> 4;
  const int uj = tid & 15;
  const int jglob = js * 16 + uj;
  const float bs_i = bias[jglob];
  const float bs_f = bias[512 + jglob];
  const float bs_g = bias[1024 + jglob];
  const float bs_o = bias[1536 + jglob];
  const float bs_d = bd[jglob];
  float c_reg = 0.0f;

  u32x4 rr[4][4];
  u32x4 xpf0, xpf1, xpf2, xpf3;           // next-step x fragments (hi0,lo0,hi1,lo1)

#define ISSUE_Q(qq) do { \
    const unsigned* sp_ = state + 2u * ((size_t)lslot * 8192 + (size_t)lw * 512 + w * 128 + (qq) * 32 + ko * 8); \
    asm volatile( \
        "global_load_dwordx4 %0, %4, off sc0 sc1\n\t" \
        "global_load_dwordx4 %1, %4, off offset:16 sc0 sc1\n\t" \
        "global_load_dwordx4 %2, %4, off offset:32 sc0 sc1\n\t" \
        "global_load_dwordx4 %3, %4, off offset:48 sc0 sc1" \
        : "=&v"(rr[qq][0]), "=&v"(rr[qq][1]), "=&v"(rr[qq][2]), "=&v"(rr[qq][3]) \
        : "v"(sp_) : "memory"); \
  } while (0)

#define TAGM(vv) (((vv)[0] & 3u) | (((vv)[1] & 3u) << 2) | (((vv)[2] & 3u) << 4) | (((vv)[3] & 3u) << 6))
#define CHKQ(qq) __all((int)((TAGM(rr[qq][0]) == P8) & (TAGM(rr[qq][1]) == P8) & \
                             (TAGM(rr[qq][2]) == P8) & (TAGM(rr[qq][3]) == P8)))

#define MFMAQ(qq) do { \
    BF8U hh_, hl_, ch_, cl_; \
    _Pragma("unroll") \
    for (int j = 0; j < 4; ++j) { \
      unsigned hw0 = rr[qq][j][0], cw0 = rr[qq][j][1]; \
      unsigned hw1 = rr[qq][j][2], cw1 = rr[qq][j][3]; \
      hh_.u[j] = __builtin_amdgcn_perm(hw1, hw0, 0x07060302u); \
      hl_.u[j] = __builtin_amdgcn_perm(hw1, hw0, 0x05040100u); \
      ch_.u[j] = __builtin_amdgcn_perm(cw1, cw0, 0x07060302u); \
      cl_.u[j] = __builtin_amdgcn_perm(cw1, cw0, 0x05040100u); \
    } \
    _Pragma("unroll") \
    for (int g4 = 0; g4 < 4; ++g4) { \
      f32x4 acc = ag[g4][(qq) & 1]; \
      acc = __builtin_amdgcn_mfma_f32_16x16x32_bf16(hh_.v, whh[g4][qq], acc, 0, 0, 0); \
      acc = __builtin_amdgcn_mfma_f32_16x16x32_bf16(hl_.v, whh[g4][qq], acc, 0, 0, 0); \
      acc = __builtin_amdgcn_mfma_f32_16x16x32_bf16(hh_.v, whl[g4][qq], acc, 0, 0, 0); \
      ag[g4][(qq) & 1] = acc; \
    } \
    { f32x4 a2 = ac[(qq) & 1]; \
      a2 = __builtin_amdgcn_mfma_f32_16x16x32_bf16(ch_.v, wdh[qq], a2, 0, 0, 0); \
      a2 = __builtin_amdgcn_mfma_f32_16x16x32_bf16(cl_.v, wdh[qq], a2, 0, 0, 0); \
      a2 = __builtin_amdgcn_mfma_f32_16x16x32_bf16(ch_.v, wdl[qq], a2, 0, 0, 0); \
      ac[(qq) & 1] = a2; } \
  } while (0)

  // ---- prologue: prefetch x fragments for t=0 ----
  if (XPK) {
    const int ts0 = dir ? (T_DIM - 1) : 0;
    const unsigned* xb = xpk + ((((size_t)ts0 * 4 + mt) * 8 + w * 2) * 64 + l) * 8;
    asm volatile(
        "global_load_dwordx4 %0, %4, off\n\t"
        "global_load_dwordx4 %1, %4, off offset:16\n\t"
        "global_load_dwordx4 %2, %5, off\n\t"
        "global_load_dwordx4 %3, %5, off offset:16"
        : "=v"(xpf0), "=v"(xpf1), "=v"(xpf2), "=v"(xpf3)
        : "v"(xb), "v"(xb + 512) : "memory");
    asm volatile("s_waitcnt vmcnt(0)" ::: "memory");
    __builtin_amdgcn_sched_barrier(0);
  }

  for (int t = 0; t < T_DIM; ++t) {
    const int tsrc = dir ? (T_DIM - 1 - t) : t;
    const int sslot = t & 1;
    const int lslot = sslot ^ 1;
    const int p = t & 1;

    // ---- top: xpf (issued last step) complete; the 2 stores may stay outstanding ----
    asm volatile("s_waitcnt vmcnt(2)" ::: "memory");
    __builtin_amdgcn_sched_barrier(0);

    float tt = tim[(size_t)tsrc * B_DIM + b0 + ub];

    bf16x8 axh[2], axl[2];
    if (XPK) {
      BF8U u0, u1, u2, u3;
      u0.u = xpf0; u1.u = xpf1; u2.u = xpf2; u3.u = xpf3;
      axh[0] = u0.v; axl[0] = u1.v; axh[1] = u2.v; axl[1] = u3.v;
    } else {
      #pragma unroll
      for (int xi = 0; xi < 2; ++xi) {
        const float* xp = x + ((size_t)tsrc * B_DIM + b0 + lw) * I_DIM + (w * 2 + xi) * 32 + ko * 8;
        f32x4 v0 = *(const f32x4*)xp;
        f32x4 v1 = *(const f32x4*)(xp + 4);
        bf16x8 vh, vl;
        #pragma unroll
        for (int i = 0; i < 4; ++i) {
          short h0 = f2bf(v0[i]); vh[i] = h0;     vl[i] = f2bf(v0[i] - bf2f(h0));
          short h1 = f2bf(v1[i]); vh[4 + i] = h1; vl[4 + i] = f2bf(v1[i] - bf2f(h1));
        }
        axh[xi] = vh; axl[xi] = vl;
      }
    }

    // ---- issue state loads FIRST (flight overlaps X MFMAs) ----
    if (t > 0) { ISSUE_Q(0); ISSUE_Q(1); ISSUE_Q(2); ISSUE_Q(3); }

    // ---- prefetch x fragments for t+1 (after state loads; retires last) ----
    if (XPK) {
      const int tn = (t + 1 < T_DIM) ? (dir ? (T_DIM - 2 - t) : (t + 1)) : 0;
      const unsigned* xbn = xpk + ((((size_t)tn * 4 + mt) * 8 + w * 2) * 64 + l) * 8;
      asm volatile(
          "global_load_dwordx4 %0, %4, off\n\t"
          "global_load_dwordx4 %1, %4, off offset:16\n\t"
          "global_load_dwordx4 %2, %5, off\n\t"
          "global_load_dwordx4 %3, %5, off offset:16"
          : "=v"(xpf0), "=v"(xpf1), "=v"(xpf2), "=v"(xpf3)
          : "v"(xbn), "v"(xbn + 512) : "memory");
    }

    // ---- X MFMAs (hide state-load flight) ----
    f32x4 ag[4][2]; f32x4 ac[2];
    #pragma unroll
    for (int g4 = 0; g4 < 4; ++g4) { ag[g4][0] = (f32x4)0.0f; ag[g4][1] = (f32x4)0.0f; }
    ac[0] = (f32x4)0.0f; ac[1] = (f32x4)0.0f;
    #pragma unroll
    for (int xi = 0; xi < 2; ++xi) {
      #pragma unroll
      for (int g4 = 0; g4 < 4; ++g4) {
        f32x4 acc = ag[g4][xi];
        acc = __builtin_amdgcn_mfma_f32_16x16x32_bf16(axh[xi], wxh[g4][xi], acc, 0, 0, 0);
        acc = __builtin_amdgcn_mfma_f32_16x16x32_bf16(axl[xi], wxh[g4][xi], acc, 0, 0, 0);
        acc = __builtin_amdgcn_mfma_f32_16x16x32_bf16(axh[xi], wxl[g4][xi], acc, 0, 0, 0);
        ag[g4][xi] = acc;
      }
    }

    // ---- counted tag checks (N = #ops issued after target), batched retries ----
    if (t > 0) {
      const unsigned e  = (unsigned)(t - 1) & 15u;
      const unsigned eb = (e & 3u) | (((e >> 2) & 3u) << 2);
      const unsigned P8 = eb | (eb << 4);

      if constexpr (XPK) { asm volatile("s_waitcnt vmcnt(16)" ::: "memory"); }
      else               { asm volatile("s_waitcnt vmcnt(12)" ::: "memory"); }
      __builtin_amdgcn_sched_barrier(0);
      int s0 = !CHKQ(0);
      if constexpr (XPK) { asm volatile("s_waitcnt vmcnt(12)" ::: "memory"); }
      else               { asm volatile("s_waitcnt vmcnt(8)" ::: "memory"); }
      __builtin_amdgcn_sched_barrier(0);
      int s1 = !CHKQ(1);
      if constexpr (XPK) { asm volatile("s_waitcnt vmcnt(8)" ::: "memory"); }
      else               { asm volatile("s_waitcnt vmcnt(4)" ::: "memory"); }
      __builtin_amdgcn_sched_barrier(0);
      int s2 = !CHKQ(2);
      if constexpr (XPK) { asm volatile("s_waitcnt vmcnt(4)" ::: "memory"); }
      else               { asm volatile("s_waitcnt vmcnt(0)" ::: "memory"); }
      __builtin_amdgcn_sched_barrier(0);
      int s3 = !CHKQ(3);

      while (s0 | s1 | s2 | s3) {          // wave-uniform (results of __all)
        if (s0) ISSUE_Q(0);
        if (s1) ISSUE_Q(1);
        if (s2) ISSUE_Q(2);
        if (s3) ISSUE_Q(3);
        asm volatile("s_waitcnt vmcnt(0)" ::: "memory");
        __builtin_amdgcn_sched_barrier(0);
        if (s0) s0 = !CHKQ(0);
        if (s1) s1 = !CHKQ(1);
        if (s2) s2 = !CHKQ(2);
        if (s3) s3 = !CHKQ(3);
      }

      // fixed order q0..q3 -> deterministic fp accumulation
      MFMAQ(0); MFMAQ(1); MFMAQ(2); MFMAQ(3);
    }

    // ---- cross-wave reduce into red[p]; raw barrier (lgkm only, NO vmcnt drain) ----
    #pragma unroll
    for (int g4 = 0; g4 < 4; ++g4) {
      f32x4 s = ag[g4][0] + ag[g4][1];
      #pragma unroll
      for (int r = 0; r < 4; ++r) red[p][w][g4][ko * 4 + r][lw] = s[r];
    }
    {
      f32x4 s = ac[0] + ac[1];
      #pragma unroll
      for (int r = 0; r < 4; ++r) red[p][w][4][ko * 4 + r][lw] = s[r];
    }
    asm volatile("s_waitcnt lgkmcnt(0)" ::: "memory");
    __builtin_amdgcn_s_barrier();

    // ---- update + tagged state store + out store (fire-and-forget) ----
    {
      float gi = red[p][0][0][ub][uj] + red[p][1][0][ub][uj] + red[p][2][0][ub][uj] + red[p][3][0][ub][uj] + bs_i;
      float gf = red[p][0][1][ub][uj] + red[p][1][1][ub][uj] + red[p][2][1][ub][uj] + red[p][3][1][ub][uj] + bs_f;
      float gg = red[p][0][2][ub][uj] + red[p][1][2][ub][uj] + red[p][2][2][ub][uj] + red[p][3][2][ub][uj] + bs_g;
      float go = red[p][0][3][ub][uj] + red[p][1][3][ub][uj] + red[p][2][3][ub][uj] + red[p][3][3][ub][uj] + bs_o;
      float csv = red[p][0][4][ub][uj] + red[p][1][4][ub][uj] + red[p][2][4][ub][uj] + red[p][3][4][ub][uj] + bs_d;

      float c_s = tanh_f(csv);
      float dinv = 1.0f / __logf(2.718281828459045f + tt);
      float c_adj = c_reg - c_s + c_s * dinv;
      float iv = sigm(gi);
      float fv = sigm(gf);
      float ov = sigm(go);
      float gv = tanh_f(gg);
      float c_new = fv * c_adj + iv * gv;
      float h_new = ov * tanh_f(c_new);
      c_reg = c_new;

      short hh = f2bf(h_new), hl2 = f2bf(h_new - bf2f(hh));
      short ch = f2bf(c_new), cl2 = f2bf(c_new - bf2f(ch));
      const unsigned tg = (unsigned)t;
      u32x2 val;
      val[0] = ((unsigned)(unsigned short)hh << 16) | (((unsigned)(unsigned short)hl2) & 0xFFFCu) | (tg & 3u);
      val[1] = ((unsigned)(unsigned short)ch << 16) | (((unsigned)(unsigned short)cl2) & 0xFFFCu) | ((tg >> 2) & 3u);
      unsigned* sp = state + 2u * ((size_t)sslot * 8192 + (size_t)ub * 512 + jglob);
      st_u32x2(sp, val);
      out[((size_t)tsrc * B_DIM + b0 + ub) * 1024 + dir * 512 + jglob] = h_new;
    }
  }
#undef ISSUE_Q
#undef TAGM
#undef CHKQ
#undef MFMAQ
}

extern "C" void kernel_launch(void* const* d_in, const int* in_sizes, int n_in,
                              void* d_out, int out_size, void* d_ws, size_t ws_size,
                              hipStream_t stream) {
  (void)in_sizes; (void)n_in; (void)out_size;
  if (ws_size < (size_t)WS_NEED_MIN) return;  // failure signature: ws too small
  const bool use_xpk = ws_size >= (size_t)WS_NEED_XPK;

  const float* x     = (const float*)d_in[0];
  const float* tim   = (const float*)d_in[1];
  const float* Wih_f = (const float*)d_in[2];
  const float* Whh_f = (const float*)d_in[3];
  const float* b_f   = (const float*)d_in[4];
  const float* Wd_f  = (const float*)d_in[5];
  const float* bd_f  = (const float*)d_in[6];
  const float* Wih_b = (const float*)d_in[7];
  const float* Whh_b = (const float*)d_in[8];
  const float* b_b   = (const float*)d_in[9];
  const float* Wd_b  = (const float*)d_in[10];
  const float* bd_b  = (const float*)d_in[11];
  float* out = (float*)d_out;
  char* ws = (char*)d_ws;
  unsigned* xpk = (unsigned*)(ws + WS_XPK);

  hipLaunchKernelGGL(init_ws_kernel, dim3(64), dim3(256), 0, stream, (unsigned*)ws);
  if (use_xpk) {
    hipLaunchKernelGGL(xpack_kernel, dim3(4096), dim3(256), 0, stream, x, xpk);
    hipLaunchKernelGGL((lstm_kernel<true>), dim3(256), dim3(256), 0, stream,
                       x, tim, Wih_f, Whh_f, b_f, Wd_f, bd_f,
                       Wih_b, Whh_b, b_b, Wd_b, bd_b, out, ws, xpk);
  } else {
    hipLaunchKernelGGL((lstm_kernel<false>), dim3(256), dim3(256), 0, stream,
                       x, tim, Wih_f, Whh_f, b_f, Wd_f, bd_f,
                       Wih_b, Whh_b, b_b, Wd_b, bd_b, out, ws, (const unsigned*)nullptr);
  }
}

// Round 10
// 1714.219 us; speedup vs baseline: 1.7510x; 1.4730x over previous
//
#include <hip/hip_runtime.h>
#include <cstdint>

#define T_DIM 512
#define B_DIM 64
#define I_DIM 256
#define H_DIM 512

typedef _Float16 f16x8 __attribute__((ext_vector_type(8)));
typedef float f32x4  __attribute__((ext_vector_type(4)));
typedef unsigned int u32x4 __attribute__((ext_vector_type(4)));

union H8U { f16x8 v; u32x4 u; };

// ---- ws layout ----
#define WS_FLAGS   0u                          // 8 groups * 1024B; flag(g,j) at g*1024 + j*64
#define WS_STATE   8192u                       // 8 groups * 65536B
#define GRP_U32    16384u                      // per-group state: 2 slots x 16 batch x 512 k x 4B
#define WS_XPK     (8192u + 8u*65536u)         // 532480
#define XPK_U32    (512u*4u*8u*64u*4u)         // 4,194,304 u32 = 16MB
#define WS_NEED_MIN WS_XPK
#define WS_NEED_XPK (WS_XPK + XPK_U32*4u)

__device__ __forceinline__ unsigned short f2h(float f) {
  union { _Float16 h; unsigned short u; } c; c.h = (_Float16)f; return c.u;
}
__device__ __forceinline__ float sigm(float v) { return 1.0f / (1.0f + __expf(-v)); }
__device__ __forceinline__ float tanh_f(float v) {
  float e = __expf(2.0f * fabsf(v));
  float r = 1.0f - 2.0f / (e + 1.0f);
  return copysignf(r, v);
}

// agent-scope coherence-point accesses (PROVEN R2/R3/R7): sc0 sc1
__device__ __forceinline__ void st_u32(unsigned* p, unsigned v) {
  asm volatile("global_store_dword %0, %1, off sc0 sc1" :: "v"(p), "v"(v) : "memory");
}
__device__ __forceinline__ unsigned ld_u32(const unsigned* p) {
  unsigned v;
  asm volatile("global_load_dword %0, %1, off sc0 sc1\n\ts_waitcnt vmcnt(0)"
               : "=v"(v) : "v"(p) : "memory");
  return v;
}

__global__ void __launch_bounds__(256) init_ws_kernel(unsigned* ws) {
  unsigned n = WS_STATE / 4u;                  // flags region only (state needs no init)
  for (unsigned i = blockIdx.x * 256u + threadIdx.x; i < n; i += gridDim.x * 256u)
    __hip_atomic_store(&ws[i], 0u, __ATOMIC_RELAXED, __HIP_MEMORY_SCOPE_AGENT);
}

// pre-pack x into fp16 MFMA fragments: [t][mt(4)][kt(8)][lane(64)] -> 1 dwordx4 (8 halfs)
__global__ void __launch_bounds__(256) xpack_kernel(const float* __restrict__ x,
                                                    unsigned* __restrict__ xpk) {
  size_t idx = (size_t)blockIdx.x * 256 + threadIdx.x;   // 1,048,576 total
  int l = (int)(idx & 63);
  size_t kt = (idx >> 6) & 7, mt = (idx >> 9) & 3, t = idx >> 11;
  const float* xp = x + ((t * 64) + mt * 16 + (size_t)(l & 15)) * 256 + kt * 32 + (size_t)(l >> 4) * 8;
  f32x4 a = *(const f32x4*)xp, b = *(const f32x4*)(xp + 4);
  float v[8] = {a[0], a[1], a[2], a[3], b[0], b[1], b[2], b[3]};
  u32x4 pk;
  #pragma unroll
  for (int i = 0; i < 4; ++i)
    pk[i] = (unsigned)f2h(v[2 * i]) | ((unsigned)f2h(v[2 * i + 1]) << 16);
  *(u32x4*)(xpk + idx * 4) = pk;
}

// 128 blocks x 256 threads. Group g = blockIdx&7 (dir x batch-tile), 16 blocks/group,
// block owns 32 output cols (js = blockIdx>>3 in [0,16)). Wave w: x k=[64w,64w+64),
// h/c k=[128w,128w+128). fp16 operands; state granule 4B = (h16<<16)|c16.
// Sync: R7-proven flags (64B-strided, sc0 sc1). Broadcast = 4MB/step (was 16).
template <bool XPK>
__global__ void __launch_bounds__(256, 1) lstm_kernel(
    const float* __restrict__ x, const float* __restrict__ tim,
    const float* __restrict__ Wih_f, const float* __restrict__ Whh_f,
    const float* __restrict__ bias_f, const float* __restrict__ Wd_f,
    const float* __restrict__ bd_f,
    const float* __restrict__ Wih_b, const float* __restrict__ Whh_b,
    const float* __restrict__ bias_b, const float* __restrict__ Wd_b,
    const float* __restrict__ bd_b,
    float* __restrict__ out, char* __restrict__ wsb,
    const unsigned* __restrict__ xpk)
{
  const int tid = threadIdx.x;
  const int w   = tid >> 6;               // 0..3
  const int l   = tid & 63;
  const int lw  = l & 15;                 // A-frag row (batch) / B-frag col
  const int ko  = l >> 4;                 // k-octet
  const int g   = blockIdx.x & 7;
  const int js  = blockIdx.x >> 3;        // 0..15 (32-col slice)
  const int dir = g & 1;
  const int mt  = g >> 1;
  const int b0  = mt * 16;

  const float* Wih  = dir ? Wih_b  : Wih_f;
  const float* Whh  = dir ? Whh_b  : Whh_f;
  const float* bias = dir ? bias_b : bias_f;
  const float* Wd   = dir ? Wd_b   : Wd_f;
  const float* bd   = dir ? bd_b   : bd_f;

  unsigned* flagbase = (unsigned*)(wsb + WS_FLAGS) + (size_t)g * 256;   // 1KB/group
  unsigned* state = (unsigned*)(wsb + WS_STATE) + (size_t)g * GRP_U32;
  // state u32[slot(2)][batch(16)][k(512)] = (h16<<16)|c16

  __shared__ float red[4][5][16][34];     // 43.5KB; <=2-way banks

  // ---- weight preload (single fp16), persists all 512 steps: 56 f16x8 = 224 VGPR ----
  f16x8 wx[4][2][2];                      // [gate][xi][ct]
  f16x8 wh[4][4][2];                      // [gate][q][ct]
  f16x8 wd[4][2];                         // [q][ct]
  #pragma unroll
  for (int xi = 0; xi < 2; ++xi) {
    const int krow = (w * 2 + xi) * 32 + ko * 8;
    #pragma unroll
    for (int g4 = 0; g4 < 4; ++g4) {
      #pragma unroll
      for (int ct = 0; ct < 2; ++ct) {
        const float* p = Wih + (size_t)krow * 2048 + g4 * 512 + js * 32 + ct * 16 + lw;
        #pragma unroll
        for (int i = 0; i < 8; ++i) wx[g4][xi][ct][i] = (_Float16)p[(size_t)i * 2048];
      }
    }
  }
  #pragma unroll
  for (int q = 0; q < 4; ++q) {
    const int krow = w * 128 + q * 32 + ko * 8;
    #pragma unroll
    for (int g4 = 0; g4 < 4; ++g4) {
      #pragma unroll
      for (int ct = 0; ct < 2; ++ct) {
        const float* p = Whh + (size_t)krow * 2048 + g4 * 512 + js * 32 + ct * 16 + lw;
        #pragma unroll
        for (int i = 0; i < 8; ++i) wh[g4][q][ct][i] = (_Float16)p[(size_t)i * 2048];
      }
    }
    #pragma unroll
    for (int ct = 0; ct < 2; ++ct) {
      const float* p2 = Wd + (size_t)krow * 512 + js * 32 + ct * 16 + lw;
      #pragma unroll
      for (int i = 0; i < 8; ++i) wd[q][ct][i] = (_Float16)p2[(size_t)i * 512];
    }
  }

  // update mapping: thread owns (batch ub, cols uj and uj+16)
  const int ub = tid >> 4;                // 0..15
  const int uj = tid & 15;                // 0..15
  float bs_i[2], bs_f[2], bs_g[2], bs_o[2], bs_d[2], c_reg[2];
  #pragma unroll
  for (int ct = 0; ct < 2; ++ct) {
    const int jg = js * 32 + ct * 16 + uj;
    bs_i[ct] = bias[jg];
    bs_f[ct] = bias[512 + jg];
    bs_g[ct] = bias[1024 + jg];
    bs_o[ct] = bias[1536 + jg];
    bs_d[ct] = bd[jg];
    c_reg[ct] = 0.0f;
  }

  u32x4 rr[4][2];
  u32x4 xpf0, xpf1;

#define ISSUE_KT(kt) do { \
    const unsigned* sp_ = state + (size_t)lslot * 8192 + (size_t)lw * 512 + w * 128 + (kt) * 32 + ko * 8; \
    asm volatile( \
        "global_load_dwordx4 %0, %2, off sc0 sc1\n\t" \
        "global_load_dwordx4 %1, %2, off offset:16 sc0 sc1" \
        : "=&v"(rr[kt][0]), "=&v"(rr[kt][1]) : "v"(sp_) : "memory"); \
  } while (0)

#define MFMA_KT(kt) do { \
    H8U hf_, cf_; \
    hf_.u[0] = __builtin_amdgcn_perm(rr[kt][0][1], rr[kt][0][0], 0x07060302u); \
    hf_.u[1] = __builtin_amdgcn_perm(rr[kt][0][3], rr[kt][0][2], 0x07060302u); \
    hf_.u[2] = __builtin_amdgcn_perm(rr[kt][1][1], rr[kt][1][0], 0x07060302u); \
    hf_.u[3] = __builtin_amdgcn_perm(rr[kt][1][3], rr[kt][1][2], 0x07060302u); \
    cf_.u[0] = __builtin_amdgcn_perm(rr[kt][0][1], rr[kt][0][0], 0x05040100u); \
    cf_.u[1] = __builtin_amdgcn_perm(rr[kt][0][3], rr[kt][0][2], 0x05040100u); \
    cf_.u[2] = __builtin_amdgcn_perm(rr[kt][1][1], rr[kt][1][0], 0x05040100u); \
    cf_.u[3] = __builtin_amdgcn_perm(rr[kt][1][3], rr[kt][1][2], 0x05040100u); \
    _Pragma("unroll") \
    for (int g4 = 0; g4 < 4; ++g4) { \
      _Pragma("unroll") \
      for (int ct = 0; ct < 2; ++ct) \
        ag[g4][ct] = __builtin_amdgcn_mfma_f32_16x16x32_f16(hf_.v, wh[g4][kt][ct], ag[g4][ct], 0, 0, 0); \
    } \
    _Pragma("unroll") \
    for (int ct = 0; ct < 2; ++ct) \
      ac[ct] = __builtin_amdgcn_mfma_f32_16x16x32_f16(cf_.v, wd[kt][ct], ac[ct], 0, 0, 0); \
  } while (0)

  // ---- prologue: prefetch x fragments for t=0 ----
  if (XPK) {
    const int ts0 = dir ? (T_DIM - 1) : 0;
    const unsigned* xb = xpk + (((size_t)ts0 * 4 + mt) * 8 + w * 2) * 256 + (size_t)l * 4;
    asm volatile(
        "global_load_dwordx4 %0, %2, off\n\t"
        "global_load_dwordx4 %1, %3, off"
        : "=v"(xpf0), "=v"(xpf1) : "v"(xb), "v"(xb + 256) : "memory");
    asm volatile("s_waitcnt vmcnt(0)" ::: "memory");
    __builtin_amdgcn_sched_barrier(0);
  }

  for (int t = 0; t < T_DIM; ++t) {
    const int tsrc = dir ? (T_DIM - 1 - t) : t;
    const int sslot = t & 1;
    const int lslot = sslot ^ 1;

    // ---- X phase: fragments ready (prefetched + drained at prev S4) ----
    float tt = tim[(size_t)tsrc * B_DIM + b0 + ub];

    f16x8 ax[2];
    if (XPK) {
      H8U u0, u1; u0.u = xpf0; u1.u = xpf1;
      ax[0] = u0.v; ax[1] = u1.v;
    } else {
      #pragma unroll
      for (int xi = 0; xi < 2; ++xi) {
        const float* xp = x + ((size_t)tsrc * B_DIM + b0 + lw) * I_DIM + (w * 2 + xi) * 32 + ko * 8;
        f32x4 v0 = *(const f32x4*)xp;
        f32x4 v1 = *(const f32x4*)(xp + 4);
        f16x8 vv;
        #pragma unroll
        for (int i = 0; i < 4; ++i) { vv[i] = (_Float16)v0[i]; vv[4 + i] = (_Float16)v1[i]; }
        ax[xi] = vv;
      }
    }

    f32x4 ag[4][2]; f32x4 ac[2];
    #pragma unroll
    for (int g4 = 0; g4 < 4; ++g4) { ag[g4][0] = (f32x4)0.0f; ag[g4][1] = (f32x4)0.0f; }
    ac[0] = (f32x4)0.0f; ac[1] = (f32x4)0.0f;

    #pragma unroll
    for (int xi = 0; xi < 2; ++xi) {
      #pragma unroll
      for (int g4 = 0; g4 < 4; ++g4) {
        #pragma unroll
        for (int ct = 0; ct < 2; ++ct)
          ag[g4][ct] = __builtin_amdgcn_mfma_f32_16x16x32_f16(ax[xi], wx[g4][xi][ct], ag[g4][ct], 0, 0, 0);
      }
    }

    // ---- W0: wait for all 16 producer flags (lanes 0..15, 64B-strided) ----
    if (t > 0) {
      if (l < 16) {
        const unsigned* fl = flagbase + (size_t)l * 16;
        while (ld_u32(fl) < (unsigned)t) { }
      }
      __builtin_amdgcn_sched_barrier(0);

      // ---- S1: issue 8 state loads + next-x prefetch; counted overlap ----
      ISSUE_KT(0); ISSUE_KT(1); ISSUE_KT(2); ISSUE_KT(3);
      if (XPK) {
        const int tn = (t + 1 < T_DIM) ? (dir ? (T_DIM - 2 - t) : (t + 1)) : 0;
        const unsigned* xbn = xpk + (((size_t)tn * 4 + mt) * 8 + w * 2) * 256 + (size_t)l * 4;
        asm volatile(
            "global_load_dwordx4 %0, %2, off\n\t"
            "global_load_dwordx4 %1, %3, off"
            : "=v"(xpf0), "=v"(xpf1) : "v"(xbn), "v"(xbn + 256) : "memory");
      }

      if (XPK) { asm volatile("s_waitcnt vmcnt(8)" ::: "memory"); }
      else     { asm volatile("s_waitcnt vmcnt(6)" ::: "memory"); }
      __builtin_amdgcn_sched_barrier(0);
      MFMA_KT(0);
      if (XPK) { asm volatile("s_waitcnt vmcnt(6)" ::: "memory"); }
      else     { asm volatile("s_waitcnt vmcnt(4)" ::: "memory"); }
      __builtin_amdgcn_sched_barrier(0);
      MFMA_KT(1);
      if (XPK) { asm volatile("s_waitcnt vmcnt(4)" ::: "memory"); }
      else     { asm volatile("s_waitcnt vmcnt(2)" ::: "memory"); }
      __builtin_amdgcn_sched_barrier(0);
      MFMA_KT(2);
      if (XPK) { asm volatile("s_waitcnt vmcnt(2)" ::: "memory"); }
      else     { asm volatile("s_waitcnt vmcnt(0)" ::: "memory"); }
      __builtin_amdgcn_sched_barrier(0);
      MFMA_KT(3);
    } else if (XPK) {
      // t==0: issue t=1 x prefetch only
      const int tn = dir ? (T_DIM - 2) : 1;
      const unsigned* xbn = xpk + (((size_t)tn * 4 + mt) * 8 + w * 2) * 256 + (size_t)l * 4;
      asm volatile(
          "global_load_dwordx4 %0, %2, off\n\t"
          "global_load_dwordx4 %1, %3, off"
          : "=v"(xpf0), "=v"(xpf1) : "v"(xbn), "v"(xbn + 256) : "memory");
    }

    // ---- S2b: cross-wave reduce via LDS; raw lgkm barrier (no vmcnt drain) ----
    #pragma unroll
    for (int g4 = 0; g4 < 4; ++g4) {
      #pragma unroll
      for (int ct = 0; ct < 2; ++ct) {
        f32x4 s = ag[g4][ct];
        #pragma unroll
        for (int r = 0; r < 4; ++r) red[w][g4][ko * 4 + r][ct * 16 + lw] = s[r];
      }
    }
    #pragma unroll
    for (int ct = 0; ct < 2; ++ct) {
      f32x4 s = ac[ct];
      #pragma unroll
      for (int r = 0; r < 4; ++r) red[w][4][ko * 4 + r][ct * 16 + lw] = s[r];
    }
    asm volatile("s_waitcnt lgkmcnt(0)" ::: "memory");
    __builtin_amdgcn_s_barrier();

    // ---- S3: elementwise update (2 cols/thread) + state/out stores ----
    const float dinv = 1.0f / __logf(2.718281828459045f + tt);
    #pragma unroll
    for (int ct = 0; ct < 2; ++ct) {
      const int cj = ct * 16 + uj;
      float gi = red[0][0][ub][cj] + red[1][0][ub][cj] + red[2][0][ub][cj] + red[3][0][ub][cj] + bs_i[ct];
      float gf = red[0][1][ub][cj] + red[1][1][ub][cj] + red[2][1][ub][cj] + red[3][1][ub][cj] + bs_f[ct];
      float gg = red[0][2][ub][cj] + red[1][2][ub][cj] + red[2][2][ub][cj] + red[3][2][ub][cj] + bs_g[ct];
      float go = red[0][3][ub][cj] + red[1][3][ub][cj] + red[2][3][ub][cj] + red[3][3][ub][cj] + bs_o[ct];
      float csv = red[0][4][ub][cj] + red[1][4][ub][cj] + red[2][4][ub][cj] + red[3][4][ub][cj] + bs_d[ct];

      float c_s = tanh_f(csv);
      float c_adj = c_reg[ct] - c_s + c_s * dinv;
      float iv = sigm(gi);
      float fv = sigm(gf);
      float ov = sigm(go);
      float gv = tanh_f(gg);
      float c_new = fv * c_adj + iv * gv;
      float h_new = ov * tanh_f(c_new);
      c_reg[ct] = c_new;

      const int jglob = js * 32 + cj;
      unsigned val = ((unsigned)f2h(h_new) << 16) | (unsigned)f2h(c_new);
      unsigned* sp = state + (size_t)sslot * 8192 + (size_t)ub * 512 + jglob;
      st_u32(sp, val);
      out[((size_t)tsrc * B_DIM + b0 + ub) * 1024 + dir * 512 + jglob] = h_new;
    }

    // ---- S4: drain all stores (+xpf), barrier, single flag release ----
    asm volatile("s_waitcnt vmcnt(0)" ::: "memory");
    __syncthreads();
    if (tid == 0) st_u32(flagbase + (size_t)js * 16, (unsigned)(t + 1));
  }
#undef ISSUE_KT
#undef MFMA_KT
}

extern "C" void kernel_launch(void* const* d_in, const int* in_sizes, int n_in,
                              void* d_out, int out_size, void* d_ws, size_t ws_size,
                              hipStream_t stream) {
  (void)in_sizes; (void)n_in; (void)out_size;
  if (ws_size < (size_t)WS_NEED_MIN) return;  // failure signature: ws too small
  const bool use_xpk = ws_size >= (size_t)WS_NEED_XPK;

  const float* x     = (const float*)d_in[0];
  const float* tim   = (const float*)d_in[1];
  const float* Wih_f = (const float*)d_in[2];
  const float* Whh_f = (const float*)d_in[3];
  const float* b_f   = (const float*)d_in[4];
  const float* Wd_f  = (const float*)d_in[5];
  const float* bd_f  = (const float*)d_in[6];
  const float* Wih_b = (const float*)d_in[7];
  const float* Whh_b = (const float*)d_in[8];
  const float* b_b   = (const float*)d_in[9];
  const float* Wd_b  = (const float*)d_in[10];
  const float* bd_b  = (const float*)d_in[11];
  float* out = (float*)d_out;
  char* ws = (char*)d_ws;
  unsigned* xpk = (unsigned*)(ws + WS_XPK);

  hipLaunchKernelGGL(init_ws_kernel, dim3(8), dim3(256), 0, stream, (unsigned*)ws);
  if (use_xpk) {
    hipLaunchKernelGGL(xpack_kernel, dim3(4096), dim3(256), 0, stream, x, xpk);
    hipLaunchKernelGGL((lstm_kernel<true>), dim3(128), dim3(256), 0, stream,
                       x, tim, Wih_f, Whh_f, b_f, Wd_f, bd_f,
                       Wih_b, Whh_b, b_b, Wd_b, bd_b, out, ws, xpk);
  } else {
    hipLaunchKernelGGL((lstm_kernel<false>), dim3(128), dim3(256), 0, stream,
                       x, tim, Wih_f, Whh_f, b_f, Wd_f, bd_f,
                       Wih_b, Whh_b, b_b, Wd_b, bd_b, out, ws, (const unsigned*)nullptr);
  }
}